// Round 2
// baseline (685.899 us; speedup 1.0000x reference)
//
#include <hip/hip_runtime.h>

#define S 4
#define B 64
#define D 32
#define N 784
#define P 2
#define L 10
#define HALF 392
#define NSTEP 391  // HALF - 1

// Broadcast lane `lane`'s value of v to all lanes (v_readlane -> SGPR).
__device__ __forceinline__ float bcast(float v, int lane) {
    return __uint_as_float(__builtin_amdgcn_readlane(__float_as_uint(v), lane));
}

// ---- left side helpers: lane (p,j) reads column M[i][p][j], i=0..31 ----
__device__ __forceinline__ void load_col(float (&buf)[32], const float* __restrict__ Mcol) {
    #pragma unroll
    for (int i = 0; i < 32; ++i) buf[i] = Mcol[i * (P * D)];
}

__device__ __forceinline__ float step_left(float v, const float (&buf)[32],
                                           float x0, float x1, int p) {
    float t0 = 0.f, t1 = 0.f, t2 = 0.f, t3 = 0.f;
    #pragma unroll
    for (int i = 0; i < 32; i += 4) {
        t0 = fmaf(bcast(v, i + 0), buf[i + 0], t0);
        t1 = fmaf(bcast(v, i + 1), buf[i + 1], t1);
        t2 = fmaf(bcast(v, i + 2), buf[i + 2], t2);
        t3 = fmaf(bcast(v, i + 3), buf[i + 3], t3);
    }
    const float t     = (t0 + t1) + (t2 + t3);
    const float other = __shfl_xor(t, 32);
    return (p == 0) ? fmaf(x0, t, x1 * other) : fmaf(x1, t, x0 * other);
}

// ---- right side helpers: lane (p,i) reads row M[i][p][0..31] as 8 float4 ----
__device__ __forceinline__ void load_row(float4 (&buf)[8], const float4* __restrict__ R4) {
    #pragma unroll
    for (int q = 0; q < 8; ++q) buf[q] = R4[q];
}

__device__ __forceinline__ float step_right(float v, const float4 (&buf)[8],
                                            float x0, float x1, int p) {
    float t0 = 0.f, t1 = 0.f, t2 = 0.f, t3 = 0.f;
    #pragma unroll
    for (int q = 0; q < 8; ++q) {
        t0 = fmaf(buf[q].x, bcast(v, 4 * q + 0), t0);
        t1 = fmaf(buf[q].y, bcast(v, 4 * q + 1), t1);
        t2 = fmaf(buf[q].z, bcast(v, 4 * q + 2), t2);
        t3 = fmaf(buf[q].w, bcast(v, 4 * q + 3), t3);
    }
    const float t     = (t0 + t1) + (t2 + t3);
    const float other = __shfl_xor(t, 32);
    return (p == 0) ? fmaf(x0, t, x1 * other) : fmaf(x1, t, x0 * other);
}

// One wave per (side, s, b) chain. 2-deep register ping-pong prefetch of the
// A-slices + x-pairs so global-load latency hides under the FMA chain.
__global__ __launch_bounds__(64) void chain_kernel(
    const float* __restrict__ x,        // (B, N, P)
    const float* __restrict__ A_first,  // (S, D, P)
    const float* __restrict__ A_left,   // (S, 391, D, P, D)
    const float* __restrict__ A_right,  // (S, 391, D, P, D)
    const float* __restrict__ A_last,   // (S, D, P)
    float* __restrict__ ws_v)           // [side][s][b][D]
{
    const int blk  = blockIdx.x;   // 512 blocks
    const int pair = blk & 7;      // side*4 + s -> same (side,s) shares an XCD
    const int b    = blk >> 3;     // 0..63
    const int side = pair >> 2;
    const int s    = pair & 3;
    const int lane = threadIdx.x;  // 0..63
    const int p    = lane >> 5;
    const int j    = lane & 31;

    const float*  xb  = x + b * (N * P);
    const float2* xb2 = reinterpret_cast<const float2*>(xb);
    float v;

    if (side == 0) {
        const float a0 = A_first[s * D * P + j * P + 0];
        const float a1 = A_first[s * D * P + j * P + 1];
        v = fmaf(a0, xb[0], a1 * xb[1]);
        const float* Abase = A_left + (size_t)s * (NSTEP * D * P * D) + p * D + j;

        float bufA[32], bufB[32];
        float2 xA, xB;
        load_col(bufA, Abase + 0 * (D * P * D));  // slice n=1
        load_col(bufB, Abase + 1 * (D * P * D));  // slice n=2
        xA = xb2[1];
        xB = xb2[2];

        for (int k = 1; k + 1 <= NSTEP; k += 2) {
            // stage A: compute step k, prefetch slice k+2
            v = step_left(v, bufA, xA.x, xA.y, p);
            load_col(bufA, Abase + (size_t)(k + 1) * (D * P * D));   // (k+2)-1
            xA = xb2[k + 2];
            // stage B: compute step k+1, prefetch slice min(k+3, NSTEP)
            v = step_left(v, bufB, xB.x, xB.y, p);
            const int nb = (k + 3 <= NSTEP) ? (k + 3) : NSTEP;
            load_col(bufB, Abase + (size_t)(nb - 1) * (D * P * D));
            xB = xb2[nb];
        }
        v = step_left(v, bufA, xA.x, xA.y, p);  // step 391
    } else {
        const float a0 = A_last[s * D * P + j * P + 0];
        const float a1 = A_last[s * D * P + j * P + 1];
        v = fmaf(a0, xb[(N - 1) * P + 0], a1 * xb[(N - 1) * P + 1]);
        const float* Arow = A_right + (size_t)s * (NSTEP * D * P * D)
                          + j * (P * D) + p * D;

        float4 bufA[8], bufB[8];
        float2 xA, xB;
        load_row(bufA, reinterpret_cast<const float4*>(Arow + (size_t)(NSTEP - 1) * (D * P * D)));
        load_row(bufB, reinterpret_cast<const float4*>(Arow + (size_t)(NSTEP - 2) * (D * P * D)));
        xA = xb2[HALF + NSTEP - 1];
        xB = xb2[HALF + NSTEP - 2];

        for (int k = NSTEP - 1; k >= 2; k -= 2) {
            // stage A: compute step k, prefetch slice k-2
            v = step_right(v, bufA, xA.x, xA.y, p);
            load_row(bufA, reinterpret_cast<const float4*>(Arow + (size_t)(k - 2) * (D * P * D)));
            xA = xb2[HALF + k - 2];
            // stage B: compute step k-1, prefetch slice max(k-3, 0)
            v = step_right(v, bufB, xB.x, xB.y, p);
            const int mb = (k >= 3) ? (k - 3) : 0;
            load_row(bufB, reinterpret_cast<const float4*>(Arow + (size_t)mb * (D * P * D)));
            xB = xb2[HALF + mb];
        }
        v = step_right(v, bufA, xA.x, xA.y, p);  // step m=0
    }
    if (p == 0)
        ws_v[(side * S + s) * (B * D) + b * D + j] = v;
}

// Per (s,b): out_l = sum_j (sum_d v[d] * A_label[s][d][l][j]) * r[j]
__global__ __launch_bounds__(64) void label_kernel(
    const float* __restrict__ ws_v,     // [side][s][b][D]
    const float* __restrict__ A_label,  // (S, D, L, D)
    float* __restrict__ ws_o)           // [b][l][s]
{
    const int blk  = blockIdx.x;  // S*B = 256
    const int s    = blk & 3;
    const int b    = blk >> 2;
    const int lane = threadIdx.x;
    const int h    = lane >> 5;   // label half: h=0 -> l=0..4, h=1 -> l=5..9
    const int j    = lane & 31;

    const float vj = ws_v[(0 * S + s) * (B * D) + b * D + j];
    const float rj = ws_v[(1 * S + s) * (B * D) + b * D + j];

    #pragma unroll
    for (int q = 0; q < 5; ++q) {
        const int l = h * 5 + q;
        float w = 0.f;
        #pragma unroll
        for (int d = 0; d < D; ++d)
            w = fmaf(bcast(vj, d), A_label[((s * D + d) * L + l) * D + j], w);
        float c = w * rj;
        c += __shfl_xor(c, 1);
        c += __shfl_xor(c, 2);
        c += __shfl_xor(c, 4);
        c += __shfl_xor(c, 8);
        c += __shfl_xor(c, 16);
        if (j == 0) ws_o[(b * L + l) * S + s] = c;
    }
}

__global__ void prod_kernel(const float* __restrict__ ws_o, float* __restrict__ out) {
    const int t = blockIdx.x * blockDim.x + threadIdx.x;
    if (t < B * L) {
        const float* o = ws_o + t * S;
        out[t] = o[0] * o[1] * o[2] * o[3];
    }
}

extern "C" void kernel_launch(void* const* d_in, const int* in_sizes, int n_in,
                              void* d_out, int out_size, void* d_ws, size_t ws_size,
                              hipStream_t stream) {
    const float* x       = (const float*)d_in[0];
    const float* A_first = (const float*)d_in[1];
    const float* A_left  = (const float*)d_in[2];
    const float* A_label = (const float*)d_in[3];
    const float* A_right = (const float*)d_in[4];
    const float* A_last  = (const float*)d_in[5];
    float* out  = (float*)d_out;
    float* ws_v = (float*)d_ws;               // 2*S*B*D = 16384 floats
    float* ws_o = ws_v + 2 * S * B * D;       // B*L*S  =  2560 floats

    chain_kernel<<<dim3(2 * S * B), dim3(64), 0, stream>>>(
        x, A_first, A_left, A_right, A_last, ws_v);
    label_kernel<<<dim3(S * B), dim3(64), 0, stream>>>(ws_v, A_label, ws_o);
    prod_kernel<<<dim3((B * L + 255) / 256), dim3(256), 0, stream>>>(ws_o, out);
}

// Round 3
// 181.882 us; speedup vs baseline: 3.7711x; 3.7711x over previous
//
#include <hip/hip_runtime.h>
#include <stdint.h>

#define S 4
#define B 64
#define D 32
#define N 784
#define P 2
#define L 10
#define HALF 392
#define NSTEP 391

#define NSLOT 6          // LDS ring slots
#define DPREF 4          // prefetch distance (steps)
#define WAVES 4          // waves (b-chains) per block
#define SLICE_FLOATS (D * P * D)            // 2048 floats = 8 KB
#define LDS_FLOATS (NSLOT * SLICE_FLOATS + WAVES * 392 * 2)

// Broadcast lane `lane`'s value (v_readlane -> SGPR operand).
__device__ __forceinline__ float bcast(float v, int lane) {
    return __uint_as_float(__builtin_amdgcn_readlane(__float_as_uint(v), lane));
}

// Async global->LDS, 16B per lane. LDS dest is wave-uniform base + lane*16.
__device__ __forceinline__ void gload16(const void* g, void* l) {
    __builtin_amdgcn_global_load_lds(
        (const __attribute__((address_space(1))) uint32_t*)g,
        (__attribute__((address_space(3))) uint32_t*)l,
        16, 0, 0);
}

// Stage one 8KB slice cooperatively: wave w covers 16B-chunks [w*128, w*128+128).
// swz: XOR chunk swizzle (right side) so swizzled b128 LDS reads are spread
// across bank groups; source is pre-swizzled, LDS dest stays linear (rule #21).
__device__ __forceinline__ void stage_slice(const float* gbase, float* lbase,
                                            int w, int lane, bool swz) {
    #pragma unroll
    for (int c = 0; c < 2; ++c) {
        const int lin = w * 128 + c * 64 + lane;
        const int src = swz ? (lin ^ ((lin >> 4) & 7)) : lin;
        gload16((const char*)gbase + (size_t)src * 16,
                (char*)lbase + (size_t)(w * 128 + c * 64) * 16);
    }
}

// One step of the chain. T may be a runtime loop var (main) or literal (tail).
// Order: [issue prefetch][counted vmcnt][barrier][fence][compute from LDS].
#define STEP_BODY(T, WAITSTR, DO_ISSUE)                                        \
    {                                                                          \
        if (DO_ISSUE) {                                                        \
            const int slice = side ? (NSTEP - 1 - ((T) + DPREF)) : ((T) + DPREF); \
            stage_slice(Abase + (size_t)slice * SLICE_FLOATS,                  \
                        &lds[(((T) + DPREF) % NSLOT) * SLICE_FLOATS],          \
                        w, lane, side != 0);                                   \
        }                                                                      \
        asm volatile(WAITSTR ::: "memory");                                    \
        __builtin_amdgcn_s_barrier();                                          \
        asm volatile("" ::: "memory");                                         \
        const float* sl = &lds[((T) % NSLOT) * SLICE_FLOATS];                  \
        const float2 xp = xsh[w * 392 + (T)];                                  \
        float t0 = 0.f, t1 = 0.f, t2 = 0.f, t3 = 0.f;                          \
        if (side == 0) {                                                       \
            _Pragma("unroll")                                                  \
            for (int i = 0; i < 32; i += 4) {                                  \
                t0 = fmaf(bcast(v, i + 0), sl[(i + 0) * 64 + p * 32 + jj], t0);\
                t1 = fmaf(bcast(v, i + 1), sl[(i + 1) * 64 + p * 32 + jj], t1);\
                t2 = fmaf(bcast(v, i + 2), sl[(i + 2) * 64 + p * 32 + jj], t2);\
                t3 = fmaf(bcast(v, i + 3), sl[(i + 3) * 64 + p * 32 + jj], t3);\
            }                                                                  \
        } else {                                                               \
            _Pragma("unroll")                                                  \
            for (int q = 0; q < 8; ++q) {                                      \
                const int phys = (jj * 16 + p * 8 + q) ^ (jj & 7);             \
                const float4 rv = *(const float4*)&sl[phys * 4];               \
                t0 = fmaf(rv.x, bcast(v, q * 4 + 0), t0);                      \
                t1 = fmaf(rv.y, bcast(v, q * 4 + 1), t1);                      \
                t2 = fmaf(rv.z, bcast(v, q * 4 + 2), t2);                      \
                t3 = fmaf(rv.w, bcast(v, q * 4 + 3), t3);                      \
            }                                                                  \
        }                                                                      \
        const float tt    = (t0 + t1) + (t2 + t3);                             \
        const float other = __shfl_xor(tt, 32);                                \
        v = (p == 0) ? fmaf(xp.x, tt, xp.y * other)                            \
                     : fmaf(xp.y, tt, xp.x * other);                           \
    }

// Block = 4 waves = 4 b-chains of one (side,s); slice staged to LDS once,
// shared by all 4 waves. blockIdx&7 = (side,s) so an A-stream stays on one XCD.
__global__ __launch_bounds__(256) void chain_kernel(
    const float* __restrict__ x,        // (B, N, P)
    const float* __restrict__ A_first,  // (S, D, P)
    const float* __restrict__ A_left,   // (S, 391, D, P, D)
    const float* __restrict__ A_right,  // (S, 391, D, P, D)
    const float* __restrict__ A_last,   // (S, D, P)
    float* __restrict__ ws_v)           // [side][s][b][D]
{
    __shared__ float lds[LDS_FLOATS];

    const int blk  = blockIdx.x;   // 128 blocks
    const int pair = blk & 7;
    const int side = pair >> 2;
    const int s    = pair & 3;
    const int bg   = blk >> 3;     // 0..15
    const int tid  = threadIdx.x;
    const int w    = tid >> 6;     // wave 0..3
    const int lane = tid & 63;
    const int p    = lane >> 5;
    const int jj   = lane & 31;
    const int b    = bg * WAVES + w;

    const float2* xb2 = (const float2*)(x + (size_t)b * (N * P));
    float2* xsh = (float2*)&lds[NSLOT * SLICE_FLOATS];

    // Stage this wave's per-step x-pairs into LDS (so the main loop has no
    // global loads besides staging -> counted vmcnt stays exact).
    for (int t = lane; t < NSTEP; t += 64)
        xsh[w * 392 + t] = side ? xb2[HALF + (NSTEP - 1) - t] : xb2[t + 1];

    // Initial vector.
    float v;
    if (side == 0) {
        v = fmaf(A_first[s * D * P + jj * P + 0], xb2[0].x,
                 A_first[s * D * P + jj * P + 1] * xb2[0].y);
    } else {
        v = fmaf(A_last[s * D * P + jj * P + 0], xb2[N - 1].x,
                 A_last[s * D * P + jj * P + 1] * xb2[N - 1].y);
    }
    const float* Abase = (side ? A_right : A_left) + (size_t)s * (NSTEP * SLICE_FLOATS);

    __syncthreads();  // x staged + drains all prior vmem (vmcnt=0 from here)

    // Ring prologue: prefetch slices for steps 0..3 into slots 0..3.
    #pragma unroll
    for (int s0 = 0; s0 < DPREF; ++s0) {
        const int slice = side ? (NSTEP - 1 - s0) : s0;
        stage_slice(Abase + (size_t)slice * SLICE_FLOATS,
                    &lds[s0 * SLICE_FLOATS], w, lane, side != 0);
    }

    // Main loop: issue slot t+4, wait vmcnt(8) (slices t+1..t+4 in flight),
    // one barrier per step. Never drains to 0 until the tail.
    for (int t = 0; t < NSTEP - DPREF; ++t)
        STEP_BODY(t, "s_waitcnt vmcnt(8)", 1);
    STEP_BODY(NSTEP - 4, "s_waitcnt vmcnt(6)", 0);
    STEP_BODY(NSTEP - 3, "s_waitcnt vmcnt(4)", 0);
    STEP_BODY(NSTEP - 2, "s_waitcnt vmcnt(2)", 0);
    STEP_BODY(NSTEP - 1, "s_waitcnt vmcnt(0)", 0);

    if (p == 0)
        ws_v[(side * S + s) * (B * D) + b * D + jj] = v;
}

// Per (s,b): out_l = sum_j (sum_d v[d] * A_label[s][d][l][j]) * r[j]
__global__ __launch_bounds__(64) void label_kernel(
    const float* __restrict__ ws_v,     // [side][s][b][D]
    const float* __restrict__ A_label,  // (S, D, L, D)
    float* __restrict__ ws_o)           // [b][l][s]
{
    const int blk  = blockIdx.x;  // S*B = 256
    const int s    = blk & 3;
    const int b    = blk >> 2;
    const int lane = threadIdx.x;
    const int h    = lane >> 5;
    const int j    = lane & 31;

    const float vj = ws_v[(0 * S + s) * (B * D) + b * D + j];
    const float rj = ws_v[(1 * S + s) * (B * D) + b * D + j];

    #pragma unroll
    for (int q = 0; q < 5; ++q) {
        const int l = h * 5 + q;
        float wsum = 0.f;
        #pragma unroll
        for (int d = 0; d < D; ++d)
            wsum = fmaf(bcast(vj, d), A_label[((s * D + d) * L + l) * D + j], wsum);
        float c = wsum * rj;
        c += __shfl_xor(c, 1);
        c += __shfl_xor(c, 2);
        c += __shfl_xor(c, 4);
        c += __shfl_xor(c, 8);
        c += __shfl_xor(c, 16);
        if (j == 0) ws_o[(b * L + l) * S + s] = c;
    }
}

__global__ void prod_kernel(const float* __restrict__ ws_o, float* __restrict__ out) {
    const int t = blockIdx.x * blockDim.x + threadIdx.x;
    if (t < B * L) {
        const float* o = ws_o + t * S;
        out[t] = o[0] * o[1] * o[2] * o[3];
    }
}

extern "C" void kernel_launch(void* const* d_in, const int* in_sizes, int n_in,
                              void* d_out, int out_size, void* d_ws, size_t ws_size,
                              hipStream_t stream) {
    const float* x       = (const float*)d_in[0];
    const float* A_first = (const float*)d_in[1];
    const float* A_left  = (const float*)d_in[2];
    const float* A_label = (const float*)d_in[3];
    const float* A_right = (const float*)d_in[4];
    const float* A_last  = (const float*)d_in[5];
    float* out  = (float*)d_out;
    float* ws_v = (float*)d_ws;               // 2*S*B*D = 16384 floats
    float* ws_o = ws_v + 2 * S * B * D;       // B*L*S  =  2560 floats

    chain_kernel<<<dim3(2 * S * B / WAVES), dim3(64 * WAVES), 0, stream>>>(
        x, A_first, A_left, A_right, A_last, ws_v);
    label_kernel<<<dim3(S * B), dim3(64), 0, stream>>>(ws_v, A_label, ws_o);
    prod_kernel<<<dim3((B * L + 255) / 256), dim3(256), 0, stream>>>(ws_o, out);
}

// Round 4
// 117.284 us; speedup vs baseline: 5.8482x; 1.5508x over previous
//
#include <hip/hip_runtime.h>
#include <stdint.h>

#define S 4
#define B 64
#define D 32
#define N 784
#define P 2
#define L 10
#define HALF 392
#define NSTEP 391
#define NPAIR 196              // 195 real pairs + 1 leftover single site
#define SLICE 4096             // floats per pair slice: 4 combos * 32*32

typedef float f4 __attribute__((ext_vector_type(4)));

__device__ __forceinline__ float bcast(float v, int lane) {
    return __uint_as_float(__builtin_amdgcn_readlane(__float_as_uint(v), lane));
}

// ---------------- precompute 1: pair matrices ----------------
// W layout (per stream,t): 16 chunk-groups q, each 64 lanes x 16B.
// lane l = c2*32 + f ; combo c = c2 + 2*(q>>3) ; chunk[r] = content[c][f][e=4*(q&7)+r]
// left:  content[c][f][e] = P_c[e][f] = sum_k A0[e][a][k]*A1[k][b][f]
// right: content[c][f][e] = Q_c[f][e] = sum_k Aa[f][a][k]*Ab[k][b][e]
__global__ __launch_bounds__(256) void pair_kernel(
    const float* __restrict__ A_left, const float* __restrict__ A_right,
    float* __restrict__ Wbuf)
{
    const int t = blockIdx.x, stream = blockIdx.y;
    const int side = stream >> 2, s = stream & 3;
    __shared__ float sA[2048], sB[2048];
    const int tid = threadIdx.x;
    const bool leftover = (t == 195);

    const float* As = (side ? A_right : A_left) + (size_t)s * (NSTEP * 2048);
    int ia, ib;
    if (side == 0) { ia = 2 * t; ib = 2 * t + 1; }
    else           { ia = 389 - 2 * t; ib = 390 - 2 * t; }
    if (leftover)  { ia = side ? 0 : 390; ib = ia; }

    const float4* ga = (const float4*)(As + (size_t)ia * 2048);
    const float4* gb = (const float4*)(As + (size_t)ib * 2048);
    ((float4*)sA)[tid] = ga[tid]; ((float4*)sA)[tid + 256] = ga[tid + 256];
    ((float4*)sB)[tid] = gb[tid]; ((float4*)sB)[tid + 256] = gb[tid + 256];
    __syncthreads();

    const int c = tid >> 6, rest = tid & 63, ff = rest >> 1, eh = rest & 1;
    const int a = c & 1, bb = c >> 1;
    float out[16];

    if (!leftover) {
        if (side == 0) {
            float col[32];
            #pragma unroll
            for (int k = 0; k < 32; ++k) col[k] = sB[k * 64 + bb * 32 + ff];
            #pragma unroll
            for (int e0 = 0; e0 < 16; ++e0) {
                const int e = eh * 16 + e0; float acc = 0.f;
                #pragma unroll
                for (int k = 0; k < 32; ++k)
                    acc = fmaf(sA[e * 64 + a * 32 + k], col[k], acc);
                out[e0] = acc;
            }
        } else {
            float row[32];
            #pragma unroll
            for (int k = 0; k < 32; ++k) row[k] = sA[ff * 64 + a * 32 + k];
            #pragma unroll
            for (int e0 = 0; e0 < 16; ++e0) {
                const int e = eh * 16 + e0; float acc = 0.f;
                #pragma unroll
                for (int k = 0; k < 32; ++k)
                    acc = fmaf(row[k], sB[k * 64 + bb * 32 + e], acc);
                out[e0] = acc;
            }
        }
    } else {
        #pragma unroll
        for (int e0 = 0; e0 < 16; ++e0) {
            const int e = eh * 16 + e0;
            out[e0] = (side == 0) ? sA[e * 64 + a * 32 + ff]
                                  : sA[ff * 64 + a * 32 + e];
        }
    }

    float* Wt = Wbuf + ((size_t)stream * NPAIR + t) * SLICE;
    #pragma unroll
    for (int q0 = 0; q0 < 4; ++q0) {
        const int qq = eh * 4 + q0;
        float4 val = make_float4(out[q0 * 4 + 0], out[q0 * 4 + 1],
                                 out[q0 * 4 + 2], out[q0 * 4 + 3]);
        ((float4*)Wt)[(bb * 8 + qq) * 64 + a * 32 + ff] = val;
    }
}

// ---------------- precompute 2: weights w[c=a+2b] = xa[a]*xb[b] ----------------
__global__ __launch_bounds__(64) void wkern(const float* __restrict__ x,
                                            float* __restrict__ wtab)
{
    const int t = blockIdx.x, side = blockIdx.y, bb = threadIdx.x;
    const float2* x2 = (const float2*)x;
    float2 xa, xb;
    if (t < 195) {
        int na, nb;
        if (side == 0) { na = 2 * t + 1; nb = 2 * t + 2; }
        else           { int ma = 389 - 2 * t; na = HALF + ma; nb = na + 1; }
        xa = x2[(size_t)bb * N + na];
        xb = x2[(size_t)bb * N + nb];
    } else {
        const int na = side ? HALF : 391;
        xa = x2[(size_t)bb * N + na];
        xb = make_float2(1.f, 0.f);
    }
    float4 w = make_float4(xa.x * xb.x, xa.y * xb.x, xa.x * xb.y, xa.y * xb.y);
    ((float4*)wtab)[((size_t)side * NPAIR + t) * 64 + bb] = w;
}

// ---------------- chain kernel: register-ring pipeline ----------------
#define GLOAD(dst, ptr, off) \
    asm volatile("global_load_dwordx4 %0, %1, off offset:" #off \
                 : "=v"(dst) : "v"(ptr))

#define ISSUE_SLOT(SL) do { \
    GLOAD(SL##0,  pA, 0); GLOAD(SL##1,  pA, 1024); GLOAD(SL##2,  pA, 2048); GLOAD(SL##3,  pA, 3072); \
    GLOAD(SL##4,  pB, 0); GLOAD(SL##5,  pB, 1024); GLOAD(SL##6,  pB, 2048); GLOAD(SL##7,  pB, 3072); \
    GLOAD(SL##8,  pC, 0); GLOAD(SL##9,  pC, 1024); GLOAD(SL##10, pC, 2048); GLOAD(SL##11, pC, 3072); \
    GLOAD(SL##12, pD, 0); GLOAD(SL##13, pD, 1024); GLOAD(SL##14, pD, 2048); GLOAD(SL##15, pD, 3072); \
    GLOAD(SL##w,  pw, 0); \
    pA += SLICE; pB += SLICE; pC += SLICE; pD += SLICE; pw += 256; \
} while (0)

#define WAIT(n) do { \
    asm volatile("s_waitcnt vmcnt(" #n ")"); \
    __builtin_amdgcn_sched_barrier(0); \
} while (0)

#define FMAQ(Rq, acc, eb) \
    acc = fmaf(Rq.x, bcast(v, eb + 0), acc); \
    acc = fmaf(Rq.y, bcast(v, eb + 1), acc); \
    acc = fmaf(Rq.z, bcast(v, eb + 2), acc); \
    acc = fmaf(Rq.w, bcast(v, eb + 3), acc);

#define CONSUME_SLOT(SL) do { \
    float a0 = 0.f, a1 = 0.f, a2 = 0.f, a3 = 0.f; \
    FMAQ(SL##0,  a0, 0)  FMAQ(SL##1,  a0, 4)  FMAQ(SL##2,  a0, 8)  FMAQ(SL##3,  a0, 12) \
    FMAQ(SL##4,  a1, 16) FMAQ(SL##5,  a1, 20) FMAQ(SL##6,  a1, 24) FMAQ(SL##7,  a1, 28) \
    FMAQ(SL##8,  a2, 0)  FMAQ(SL##9,  a2, 4)  FMAQ(SL##10, a2, 8)  FMAQ(SL##11, a2, 12) \
    FMAQ(SL##12, a3, 16) FMAQ(SL##13, a3, 20) FMAQ(SL##14, a3, 24) FMAQ(SL##15, a3, 28) \
    const float wlo = c2 ? SL##w.y : SL##w.x; \
    const float whi = c2 ? SL##w.w : SL##w.z; \
    const float part = fmaf(wlo, a0 + a1, whi * (a2 + a3)); \
    v = part + __shfl_xor(part, 32); \
} while (0)

// 256 blocks x 128 threads: block = 2 waves = 2 chains of one stream.
// blk&7 = stream (XCD-pinned); lane = (c2, f): c2 selects combo pair, f = out idx.
__global__ __launch_bounds__(128, 1) void chain_kernel(
    const float* __restrict__ x,
    const float* __restrict__ A_first, const float* __restrict__ A_last,
    const float* __restrict__ Wbuf, const float* __restrict__ wtab,
    float* __restrict__ ws_v)
{
    const int tid = threadIdx.x, wv = tid >> 6, lane = tid & 63;
    const int c2 = lane >> 5, f = lane & 31;
    const int blk = blockIdx.x, stream = blk & 7;
    const int side = stream >> 2, s = stream & 3;
    const int b = (blk >> 3) * 2 + wv;

    const float2* x2 = (const float2*)x;
    float v;
    if (side == 0) {
        const float2 a  = ((const float2*)A_first)[s * D + f];
        const float2 xx = x2[(size_t)b * N + 0];
        v = fmaf(a.x, xx.x, a.y * xx.y);
    } else {
        const float2 a  = ((const float2*)A_last)[s * D + f];
        const float2 xx = x2[(size_t)b * N + (N - 1)];
        v = fmaf(a.x, xx.x, a.y * xx.y);
    }

    const float* Wstream = Wbuf + (size_t)stream * (NPAIR * SLICE);
    const float* pA = Wstream + (size_t)lane * 4;
    const float* pB = pA + 1024;
    const float* pC = pA + 2048;
    const float* pD = pA + 3072;
    const float* pw = wtab + ((size_t)side * NPAIR) * 256 + (size_t)b * 4;

    f4 A0,A1,A2,A3,A4,A5,A6,A7,A8,A9,A10,A11,A12,A13,A14,A15,Aw;
    f4 B0,B1,B2,B3,B4,B5,B6,B7,B8,B9,B10,B11,B12,B13,B14,B15,Bw;
    f4 C0,C1,C2,C3,C4,C5,C6,C7,C8,C9,C10,C11,C12,C13,C14,C15,Cw;

    ISSUE_SLOT(A);   // t = 0
    ISSUE_SLOT(B);   // t = 1

    for (int k = 0; k < 64; ++k) {   // consumes t = 0..191
        ISSUE_SLOT(C); __builtin_amdgcn_s_barrier(); WAIT(34); CONSUME_SLOT(A);
        ISSUE_SLOT(A); __builtin_amdgcn_s_barrier(); WAIT(34); CONSUME_SLOT(B);
        ISSUE_SLOT(B); __builtin_amdgcn_s_barrier(); WAIT(34); CONSUME_SLOT(C);
    }
    ISSUE_SLOT(C);   // t = 194
    __builtin_amdgcn_s_barrier(); WAIT(34); CONSUME_SLOT(A);   // t = 192
    ISSUE_SLOT(A);   // t = 195
    __builtin_amdgcn_s_barrier(); WAIT(34); CONSUME_SLOT(B);   // t = 193
    __builtin_amdgcn_s_barrier(); WAIT(17); CONSUME_SLOT(C);   // t = 194
    __builtin_amdgcn_s_barrier(); WAIT(0);  CONSUME_SLOT(A);   // t = 195

    if (lane < 32)
        ws_v[(side * S + s) * (B * D) + b * D + f] = v;
}

// ---------------- fallback chain (round-1, used if ws too small) ----------------
__global__ __launch_bounds__(64) void chain_fb(
    const float* __restrict__ x, const float* __restrict__ A_first,
    const float* __restrict__ A_left, const float* __restrict__ A_right,
    const float* __restrict__ A_last, float* __restrict__ ws_v)
{
    const int blk = blockIdx.x, pair = blk & 7, b = blk >> 3;
    const int side = pair >> 2, s = pair & 3;
    const int lane = threadIdx.x, p = lane >> 5, j = lane & 31;
    const float* xb = x + b * (N * P);
    float v;
    if (side == 0) {
        v = fmaf(A_first[s*D*P + j*P + 0], xb[0], A_first[s*D*P + j*P + 1] * xb[1]);
        const float* Abase = A_left + (size_t)s * (NSTEP * D * P * D);
        for (int n = 1; n <= NSTEP; ++n) {
            const float* M = Abase + (n - 1) * (D * P * D) + p * D + j;
            const float x0 = xb[n*P], x1 = xb[n*P + 1];
            float t0 = 0.f, t1 = 0.f;
            #pragma unroll
            for (int i = 0; i < D; i += 2) {
                t0 = fmaf(bcast(v, i),     M[i * (P*D)],       t0);
                t1 = fmaf(bcast(v, i + 1), M[(i + 1) * (P*D)], t1);
            }
            const float t = t0 + t1, o = __shfl_xor(t, 32);
            v = (p == 0) ? fmaf(x0, t, x1 * o) : fmaf(x1, t, x0 * o);
        }
    } else {
        v = fmaf(A_last[s*D*P + j*P + 0], xb[(N-1)*P], A_last[s*D*P + j*P + 1] * xb[(N-1)*P + 1]);
        const float* Abase = A_right + (size_t)s * (NSTEP * D * P * D);
        for (int m = NSTEP - 1; m >= 0; --m) {
            const float4* R4 = (const float4*)(Abase + m * (D*P*D) + j * (P*D) + p * D);
            const float x0 = xb[(HALF+m)*P], x1 = xb[(HALF+m)*P + 1];
            float t0 = 0.f, t1 = 0.f;
            #pragma unroll
            for (int q = 0; q < 8; ++q) {
                const float4 rv = R4[q];
                t0 = fmaf(rv.x, bcast(v, 4*q+0), t0);
                t1 = fmaf(rv.y, bcast(v, 4*q+1), t1);
                t0 = fmaf(rv.z, bcast(v, 4*q+2), t0);
                t1 = fmaf(rv.w, bcast(v, 4*q+3), t1);
            }
            const float t = t0 + t1, o = __shfl_xor(t, 32);
            v = (p == 0) ? fmaf(x0, t, x1 * o) : fmaf(x1, t, x0 * o);
        }
    }
    if (p == 0) ws_v[(side*S + s)*(B*D) + b*D + j] = v;
}

// ---------------- label + product ----------------
__global__ __launch_bounds__(64) void label_kernel(
    const float* __restrict__ ws_v, const float* __restrict__ A_label,
    float* __restrict__ ws_o)
{
    const int blk = blockIdx.x, s = blk & 3, b = blk >> 2;
    const int lane = threadIdx.x, h = lane >> 5, j = lane & 31;
    const float vj = ws_v[(0*S + s)*(B*D) + b*D + j];
    const float rj = ws_v[(1*S + s)*(B*D) + b*D + j];
    #pragma unroll
    for (int q = 0; q < 5; ++q) {
        const int l = h * 5 + q;
        float w = 0.f;
        #pragma unroll
        for (int d = 0; d < D; ++d)
            w = fmaf(bcast(vj, d), A_label[((s*D + d)*L + l)*D + j], w);
        float c = w * rj;
        c += __shfl_xor(c, 1); c += __shfl_xor(c, 2); c += __shfl_xor(c, 4);
        c += __shfl_xor(c, 8); c += __shfl_xor(c, 16);
        if (j == 0) ws_o[(b*L + l)*S + s] = c;
    }
}

__global__ void prod_kernel(const float* __restrict__ ws_o, float* __restrict__ out) {
    const int t = blockIdx.x * blockDim.x + threadIdx.x;
    if (t < B * L) {
        const float* o = ws_o + t * S;
        out[t] = o[0] * o[1] * o[2] * o[3];
    }
}

extern "C" void kernel_launch(void* const* d_in, const int* in_sizes, int n_in,
                              void* d_out, int out_size, void* d_ws, size_t ws_size,
                              hipStream_t stream) {
    const float* x       = (const float*)d_in[0];
    const float* A_first = (const float*)d_in[1];
    const float* A_left  = (const float*)d_in[2];
    const float* A_label = (const float*)d_in[3];
    const float* A_right = (const float*)d_in[4];
    const float* A_last  = (const float*)d_in[5];
    float* out = (float*)d_out;

    float* ws_v = (float*)d_ws;                       // 16384 floats
    float* ws_o = ws_v + 2 * S * B * D;               // 2560 floats
    float* wtab = ws_o + B * L * S;                   // 2*196*64*4 = 100352 floats
    float* Wbuf = wtab + 2 * NPAIR * 64 * 4;          // 8*196*4096 = 6422528 floats
    const size_t need = (size_t)(16384 + 2560 + 100352 + 8 * NPAIR * SLICE) * 4;

    if (ws_size >= need) {
        pair_kernel<<<dim3(NPAIR, 8), dim3(256), 0, stream>>>(A_left, A_right, Wbuf);
        wkern<<<dim3(NPAIR, 2), dim3(64), 0, stream>>>(x, wtab);
        chain_kernel<<<dim3(256), dim3(128), 0, stream>>>(x, A_first, A_last, Wbuf, wtab, ws_v);
    } else {
        chain_fb<<<dim3(2 * S * B), dim3(64), 0, stream>>>(x, A_first, A_left, A_right, A_last, ws_v);
    }
    label_kernel<<<dim3(S * B), dim3(64), 0, stream>>>(ws_v, A_label, ws_o);
    prod_kernel<<<dim3((B * L + 255) / 256), dim3(256), 0, stream>>>(ws_o, out);
}